// Round 5
// baseline (290.910 us; speedup 1.0000x reference)
//
#include <hip/hip_runtime.h>
#include <hip/hip_bf16.h>
#include <string.h>

typedef __attribute__((ext_vector_type(8))) short short8;
typedef __attribute__((ext_vector_type(4))) float floatx4;

// B=32, T=2048, D=512, U=512, M = B*T = 65536

__device__ inline uint packbf2(float lo, float hi) {
    __hip_bfloat162 h = __float22bfloat162_rn(make_float2(lo, hi));
    uint r; memcpy(&r, &h, 4); return r;
}

__device__ inline float tanh_fast(float x) {
    x = fminf(15.f, fmaxf(-15.f, x));
    float e = __expf(2.f * x);
    return __fdividef(e - 1.f, e + 1.f);
}

// async global->LDS, 16 B per lane; lds base must be wave-uniform (HW places
// lane i at base + i*16).
__device__ inline void gload_lds16(const void* g, void* l) {
    __builtin_amdgcn_global_load_lds(
        (const __attribute__((address_space(1))) unsigned int*)g,
        (__attribute__((address_space(3))) unsigned int*)l, 16, 0, 0);
}

// ---- kernel 0 (merged): blocks 0..127 = kpack, blocks 128..383 = kdec
// kpack: W1_enc (512x512 fp32 [k][n]) -> bf16 MFMA B-frag chunks (kc,ng):
//   lane l = (n&15) + ((k&31)>>3)*16 holds 8 k-elems; store dwordx4 coalesced.
// kdec: dec[b][u] = sum_d h_dec[b][d]*W1[512+d][u] + b1[u]
__global__ void kprep(const float* __restrict__ W1, const float* __restrict__ hdec,
                      const float* __restrict__ b1, ushort* __restrict__ Wp,
                      float* __restrict__ dec) {
    if (blockIdx.x < 128) {
        int wid = blockIdx.x * 4 + (threadIdx.x >> 6);   // 0..511 chunks
        int l = threadIdx.x & 63;
        int kc = wid >> 5, ng = wid & 31;
        int m = l & 15, g = l >> 4;
        const float* src = W1 + (size_t)(kc * 32 + g * 8) * 512 + ng * 16 + m;
        uint u4[4];
        #pragma unroll
        for (int e = 0; e < 4; ++e)
            u4[e] = packbf2(src[(size_t)(2 * e) * 512], src[(size_t)(2 * e + 1) * 512]);
        *(uint4*)(Wp + (size_t)wid * 512 + l * 8) = *(uint4*)u4;
    } else {
        __shared__ float red[4][64];
        int blk = blockIdx.x - 128;
        int b = blk >> 3, ug = blk & 7;
        int tid = threadIdx.x;
        int u = ug * 64 + (tid & 63), dq = tid >> 6;
        const float* hb = hdec + b * 512 + dq * 128;
        const float* w = W1 + (size_t)(512 + dq * 128) * 512 + u;
        float a = 0.f;
        #pragma unroll 8
        for (int d = 0; d < 128; ++d)
            a += hb[d] * w[(size_t)d * 512];
        red[dq][tid & 63] = a;
        __syncthreads();
        if (tid < 64)
            dec[b * 512 + ug * 64 + tid] =
                red[0][tid] + red[1][tid] + red[2][tid] + red[3][tid] + b1[ug * 64 + tid];
    }
}

// ---- kernel 1: fused GEMM + tanh + dot(W2) -> e2
// Block: 1024 thr = 16 waves; tile 128 rows x 512 cols (full U), K-phases of 32.
// Per phase: B (32 KB) staged async via global_load_lds (frag-order source);
// A (16 KB fp32) loaded nontemporal, cvt to bf16, scattered to frag-order LDS.
// Wave (rh = w>>3, cg = w&7) computes 64 rows x 64 cols (acc 4x4 = 64 AGPR).
// e2 written directly per block (no atomics).
__global__ __launch_bounds__(1024, 4) void kgemm(
        const float* __restrict__ A, const ushort* __restrict__ Wp,
        const float* __restrict__ dec, const float* __restrict__ W2,
        float* __restrict__ e2) {
    __shared__ __align__(16) ushort As[4096];    // 8 KB: 8 A-chunks (rowtile)
    __shared__ __align__(16) ushort Bs[16384];   // 32 KB: 32 B-chunks (ng)
    __shared__ float red[16][64];                // 4 KB
    const int tid = threadIdx.x;
    const int lane = tid & 63, wave = tid >> 6;
    const int rh = wave >> 3, cg = wave & 7;
    const int r0 = blockIdx.x * 128;
    const int bIdx = blockIdx.x >> 4;            // 16 blocks per batch

    // A-staging thread mapping: row ar = tid>>3, k-local = (tid&7)*4 (4 floats)
    const int ar = tid >> 3;
    const float* agp = A + (size_t)(r0 + ar) * 512 + (tid & 7) * 4;
    // LDS frag addr: chunk (ar>>4), lane_lds = (ar&15) + (klocal>>3)*16, elem klocal&7
    ushort* asw = &As[(ar >> 4) * 512 + ((ar & 15) + ((tid & 7) >> 1) * 16) * 8 + (tid & 1) * 4];

    floatx4 acc[4][4];
    #pragma unroll
    for (int i = 0; i < 4; i++)
        #pragma unroll
        for (int j = 0; j < 4; j++) acc[i][j] = (floatx4){0.f, 0.f, 0.f, 0.f};

    for (int kc = 0; kc < 16; ++kc) {
        // async B staging: wave stages chunks 2w, 2w+1 (1 KB each)
        gload_lds16(Wp + ((size_t)(kc * 32 + wave * 2)) * 512 + lane * 8,
                    &Bs[(wave * 2) * 512]);
        gload_lds16(Wp + ((size_t)(kc * 32 + wave * 2 + 1)) * 512 + lane * 8,
                    &Bs[(wave * 2 + 1) * 512]);
        // A staging: nt float4 load -> bf16 -> LDS (b64 scatter)
        floatx4 f = __builtin_nontemporal_load((const floatx4*)(agp + kc * 32));
        uint2 u; u.x = packbf2(f.x, f.y); u.y = packbf2(f.z, f.w);
        *(uint2*)asw = u;
        __syncthreads();

        short8 afr[4];
        #pragma unroll
        for (int i = 0; i < 4; ++i)
            afr[i] = *(const short8*)&As[(rh * 4 + i) * 512 + lane * 8];
        short8 bfr[4];
        #pragma unroll
        for (int j = 0; j < 4; ++j)
            bfr[j] = *(const short8*)&Bs[(cg * 4 + j) * 512 + lane * 8];
        #pragma unroll
        for (int j = 0; j < 4; ++j)
            #pragma unroll
            for (int i = 0; i < 4; ++i)
                acc[i][j] = __builtin_amdgcn_mfma_f32_16x16x32_bf16(afr[i], bfr[j], acc[i][j], 0, 0, 0);
        __syncthreads();
    }

    // epilogue: z += dec; p = sum_u tanh(z)*W2[u]; 16-lane shfl + 8-colwave LDS reduce
    const int c = lane & 15, g = lane >> 4;
    float w2v[4], dv[4];
    #pragma unroll
    for (int j = 0; j < 4; j++) {
        int n = cg * 64 + j * 16 + c;
        w2v[j] = W2[n];
        dv[j]  = dec[bIdx * 512 + n];
    }
    #pragma unroll
    for (int i = 0; i < 4; i++) {
        #pragma unroll
        for (int r = 0; r < 4; r++) {
            float p = 0.f;
            #pragma unroll
            for (int j = 0; j < 4; j++)
                p += tanh_fast(acc[i][j][r] + dv[j]) * w2v[j];
            p += __shfl_xor(p, 1, 16);
            p += __shfl_xor(p, 2, 16);
            p += __shfl_xor(p, 4, 16);
            p += __shfl_xor(p, 8, 16);
            if (c == 0) red[wave][i * 16 + g * 4 + r] = p;
        }
    }
    __syncthreads();
    if (tid < 128) {
        int trh = tid >> 6, rr = tid & 63;
        float s = 0.f;
        #pragma unroll
        for (int w = 0; w < 8; ++w) s += red[trh * 8 + w][rr];
        e2[r0 + trh * 64 + rr] = s;
    }
}

// ---- kernel 2: per-batch relu(+b2) + softmax over T -> attn
__global__ void ksoftmax(const float* __restrict__ e2, const float* __restrict__ b2,
                         float* __restrict__ attn) {
    int b = blockIdx.x, tid = threadIdx.x;
    int lane = tid & 63, wave = tid >> 6;
    float b2v = b2[0];
    float f[8];
    float m = -1e30f;
    #pragma unroll
    for (int i = 0; i < 8; i++) {
        float z = e2[b * 2048 + i * 256 + tid] + b2v;
        f[i] = fmaxf(z, 0.f);
        m = fmaxf(m, f[i]);
    }
    #pragma unroll
    for (int off = 1; off < 64; off <<= 1) m = fmaxf(m, __shfl_xor(m, off));
    __shared__ float red[4], red2[4];
    if (lane == 0) red[wave] = m;
    __syncthreads();
    m = fmaxf(fmaxf(red[0], red[1]), fmaxf(red[2], red[3]));
    float s = 0.f;
    #pragma unroll
    for (int i = 0; i < 8; i++) { f[i] = __expf(f[i] - m); s += f[i]; }
    #pragma unroll
    for (int off = 1; off < 64; off <<= 1) s += __shfl_xor(s, off);
    if (lane == 0) red2[wave] = s;
    __syncthreads();
    s = red2[0] + red2[1] + red2[2] + red2[3];
    float inv = 1.f / s;
    #pragma unroll
    for (int i = 0; i < 8; i++)
        attn[b * 2048 + i * 256 + tid] = f[i] * inv;
}

// ---- kernel 3: partial context: part[b][ch][d] = sum_{t in 64-chunk} attn*h_enc
__global__ void kctx(const float* __restrict__ A, const float* __restrict__ attn,
                     float* __restrict__ part) {
    __shared__ float at[64];
    __shared__ float4 red[128];
    int b = blockIdx.x, ch = blockIdx.y, tid = threadIdx.x;
    if (tid < 64) at[tid] = attn[b * 2048 + ch * 64 + tid];
    __syncthreads();
    int dt = tid & 127, th = tid >> 7;
    const float* base = A + ((size_t)b * 2048 + ch * 64 + th * 32) * 512 + dt * 4;
    const float* aw = at + th * 32;
    float4 acc = (float4){0.f, 0.f, 0.f, 0.f};
    #pragma unroll 8
    for (int tt = 0; tt < 32; ++tt) {
        float a = aw[tt];
        float4 h = *(const float4*)(base + (size_t)tt * 512);
        acc.x += a * h.x; acc.y += a * h.y; acc.z += a * h.z; acc.w += a * h.w;
    }
    if (th == 1) red[dt] = acc;
    __syncthreads();
    if (th == 0) {
        float4 o = red[dt];
        float4 r; r.x = acc.x + o.x; r.y = acc.y + o.y;
        r.z = acc.z + o.z; r.w = acc.w + o.w;
        *(float4*)(part + ((size_t)b * 32 + ch) * 512 + dt * 4) = r;
    }
}

// ---- kernel 4: ctx[b][d] = sum_ch part[b][ch][d]
__global__ void kfin(const float* __restrict__ part, float* __restrict__ ctx) {
    int idx = blockIdx.x * 256 + threadIdx.x;   // 0..16383
    int b = idx >> 9, d = idx & 511;
    const float* p = part + (size_t)b * 32 * 512 + d;
    float s = 0.f;
    #pragma unroll
    for (int cI = 0; cI < 32; ++cI) s += p[cI * 512];
    ctx[idx] = s;
}

extern "C" void kernel_launch(void* const* d_in, const int* in_sizes, int n_in,
                              void* d_out, int out_size, void* d_ws, size_t ws_size,
                              hipStream_t stream) {
    const float* h_enc = (const float*)d_in[0];
    const float* h_dec = (const float*)d_in[1];
    const float* W1    = (const float*)d_in[2];
    const float* b1    = (const float*)d_in[3];
    const float* W2    = (const float*)d_in[4];
    const float* b2    = (const float*)d_in[5];
    float* out  = (float*)d_out;
    float* ctx  = out;              // 32*512
    float* attn = out + 32 * 512;   // 32*2048

    char* ws = (char*)d_ws;
    ushort* Wp = (ushort*)ws;                                    // 512 KB
    float* dec  = (float*)(ws + (512 * 512 * 2));                // 64 KB
    float* e2   = (float*)(ws + (512 * 512 * 2) + (32 * 512 * 4));              // 256 KB
    float* part = (float*)(ws + (512 * 512 * 2) + (32 * 512 * 4) + (65536 * 4)); // 2 MB

    kprep<<<384, 256, 0, stream>>>(W1, h_dec, b1, Wp, dec);
    kgemm<<<512, 1024, 0, stream>>>(h_enc, Wp, dec, W2, e2);
    ksoftmax<<<32, 256, 0, stream>>>(e2, b2, attn);
    dim3 g3(32, 32);
    kctx<<<g3, 256, 0, stream>>>(h_enc, attn, part);
    kfin<<<64, 256, 0, stream>>>(part, ctx);
}

// Round 7
// 273.507 us; speedup vs baseline: 1.0636x; 1.0636x over previous
//
#include <hip/hip_runtime.h>
#include <hip/hip_bf16.h>
#include <string.h>

typedef __attribute__((ext_vector_type(8))) short short8;
typedef __attribute__((ext_vector_type(4))) float floatx4;

// B=32, T=2048, D=512, U=512, M = B*T = 65536

__device__ inline uint packbf2(float lo, float hi) {
    __hip_bfloat162 h = __float22bfloat162_rn(make_float2(lo, hi));
    uint r; memcpy(&r, &h, 4); return r;
}

__device__ inline float tanh_fast(float x) {
    x = fminf(15.f, fmaxf(-15.f, x));
    float e = __expf(2.f * x);
    return __fdividef(e - 1.f, e + 1.f);
}

// ---- kernel 0 (merged): blocks 0..127 = kpack, blocks 128..383 = kdec
__global__ void kprep(const float* __restrict__ W1, const float* __restrict__ hdec,
                      const float* __restrict__ b1, ushort* __restrict__ Wp,
                      float* __restrict__ dec) {
    if (blockIdx.x < 128) {
        // W1_enc [k][n] fp32 -> bf16 B-frag chunks (kc,ng): lane l=(n&15)+((k&31)>>3)*16
        int wid = blockIdx.x * 4 + (threadIdx.x >> 6);   // 0..511 chunks
        int l = threadIdx.x & 63;
        int kc = wid >> 5, ng = wid & 31;
        int m = l & 15, g = l >> 4;
        const float* src = W1 + (size_t)(kc * 32 + g * 8) * 512 + ng * 16 + m;
        uint u4[4];
        #pragma unroll
        for (int e = 0; e < 4; ++e)
            u4[e] = packbf2(src[(size_t)(2 * e) * 512], src[(size_t)(2 * e + 1) * 512]);
        *(uint4*)(Wp + (size_t)wid * 512 + l * 8) = *(uint4*)u4;
    } else {
        __shared__ float red[4][64];
        int blk = blockIdx.x - 128;
        int b = blk >> 3, ug = blk & 7;
        int tid = threadIdx.x;
        int u = ug * 64 + (tid & 63), dq = tid >> 6;
        const float* hb = hdec + b * 512 + dq * 128;
        const float* w = W1 + (size_t)(512 + dq * 128) * 512 + u;
        float a = 0.f;
        #pragma unroll 8
        for (int d = 0; d < 128; ++d)
            a += hb[d] * w[(size_t)d * 512];
        red[dq][tid & 63] = a;
        __syncthreads();
        if (tid < 64)
            dec[b * 512 + ug * 64 + tid] =
                red[0][tid] + red[1][tid] + red[2][tid] + red[3][tid] + b1[ug * 64 + tid];
    }
}

// ---- kernel 1: fused GEMM + tanh + dot(W2) -> e2
// Block: 256 thr = 4 waves; tile 64 rows x 512 cols (full U) x full K=512.
// Prologue: A fp32 -> bf16 -> LDS frag-chunk order (exactly 64 KB), ONE barrier.
// K-loop (16 phases of BK=32): ZERO barriers, ZERO LDS traffic for B — B frags
// ping-pong through registers, loaded one full phase ahead (latency hidden).
// Each wave: 64 rows x 128 cols (cols wave*128..+127), acc 4x8 = 128 VGPR.
// launch_bounds(256,2): <=256 VGPR, 2 blocks/CU (LDS 65 KB), 2 waves/SIMD.
__global__ __launch_bounds__(256, 2) void kgemm(
        const float* __restrict__ A, const ushort* __restrict__ Wp,
        const float* __restrict__ dec, const float* __restrict__ W2,
        float* __restrict__ e2) {
    __shared__ __align__(16) ushort As[32768];   // 64 KB: chunk (kc*4+i), kc=K/32, i=row16
    __shared__ float red[4][64];                 // 1 KB
    const int tid = threadIdx.x;
    const int lane = tid & 63, wave = tid >> 6;  // wave = col group (128 cols each)
    const int r0 = blockIdx.x * 64;
    const int bIdx = blockIdx.x >> 5;            // 32 blocks per batch

    const ushort* wp = Wp + (size_t)lane * 8 + (size_t)(wave * 8) * 512;
    #define BLOAD(dst, kc) do {                                            \
        _Pragma("unroll")                                                  \
        for (int j = 0; j < 8; ++j)                                        \
            dst[j] = *(const short8*)(wp + ((size_t)(kc) * 32 + j) * 512); \
    } while (0)

    short8 bA[8], bB[8];
    BLOAD(bA, 0);                                // phase-0 B in flight

    // ---- prologue: A tile fp32 -> bf16 -> LDS frag order (conflict-free b128)
    {
        const int m = lane & 15, g = lane >> 4;
        #pragma unroll
        for (int cc = 0; cc < 16; ++cc) {
            int chunk = wave * 16 + cc;          // 0..63 = kc*4 + i
            int kc = chunk >> 2, i = chunk & 3;
            const float* gp = A + (size_t)(r0 + i * 16 + m) * 512 + kc * 32 + g * 8;
            floatx4 f0 = *(const floatx4*)gp;
            floatx4 f1 = *(const floatx4*)(gp + 4);
            uint4 u;
            u.x = packbf2(f0.x, f0.y); u.y = packbf2(f0.z, f0.w);
            u.z = packbf2(f1.x, f1.y); u.w = packbf2(f1.z, f1.w);
            *(uint4*)&As[chunk * 512 + lane * 8] = u;
        }
    }
    __syncthreads();

    floatx4 acc[4][8];
    #pragma unroll
    for (int i = 0; i < 4; i++)
        #pragma unroll
        for (int j = 0; j < 8; j++) acc[i][j] = (floatx4){0.f, 0.f, 0.f, 0.f};

    #define COMPUTE(kc, bfr) do {                                             \
        short8 afr[4];                                                        \
        _Pragma("unroll")                                                     \
        for (int i = 0; i < 4; ++i)                                           \
            afr[i] = *(const short8*)&As[((kc) * 4 + i) * 512 + lane * 8];    \
        _Pragma("unroll")                                                     \
        for (int i = 0; i < 4; ++i)                                           \
            _Pragma("unroll")                                                 \
            for (int j = 0; j < 8; ++j)                                       \
                acc[i][j] = __builtin_amdgcn_mfma_f32_16x16x32_bf16(          \
                    afr[i], bfr[j], acc[i][j], 0, 0, 0);                      \
    } while (0)

    #pragma unroll
    for (int kc = 0; kc < 16; kc += 2) {
        BLOAD(bB, kc + 1);                       // prefetch next phase
        COMPUTE(kc, bA);
        if (kc < 14) BLOAD(bA, kc + 2);          // prefetch phase after
        COMPUTE(kc + 1, bB);
    }

    // ---- epilogue: z += dec; p = sum_u tanh(z)*W2[u]; shfl + cross-wave reduce
    const int c = lane & 15, g = lane >> 4;
    float w2v[8], dv[8];
    #pragma unroll
    for (int j = 0; j < 8; j++) {
        int n = wave * 128 + j * 16 + c;
        w2v[j] = W2[n];
        dv[j]  = dec[bIdx * 512 + n];
    }
    #pragma unroll
    for (int i = 0; i < 4; i++) {
        #pragma unroll
        for (int r = 0; r < 4; r++) {
            float p = 0.f;
            #pragma unroll
            for (int j = 0; j < 8; j++)
                p += tanh_fast(acc[i][j][r] + dv[j]) * w2v[j];
            p += __shfl_xor(p, 1, 16);
            p += __shfl_xor(p, 2, 16);
            p += __shfl_xor(p, 4, 16);
            p += __shfl_xor(p, 8, 16);
            if (c == 0) red[wave][i * 16 + g * 4 + r] = p;
        }
    }
    __syncthreads();
    if (tid < 64)
        e2[r0 + tid] = red[0][tid] + red[1][tid] + red[2][tid] + red[3][tid];
    #undef BLOAD
    #undef COMPUTE
}

// ---- kernel 2: per-batch relu(+b2) + softmax over T -> attn
__global__ void ksoftmax(const float* __restrict__ e2, const float* __restrict__ b2,
                         float* __restrict__ attn) {
    int b = blockIdx.x, tid = threadIdx.x;
    int lane = tid & 63, wave = tid >> 6;
    float b2v = b2[0];
    float f[8];
    float m = -1e30f;
    #pragma unroll
    for (int i = 0; i < 8; i++) {
        float z = e2[b * 2048 + i * 256 + tid] + b2v;
        f[i] = fmaxf(z, 0.f);
        m = fmaxf(m, f[i]);
    }
    #pragma unroll
    for (int off = 1; off < 64; off <<= 1) m = fmaxf(m, __shfl_xor(m, off));
    __shared__ float red[4], red2[4];
    if (lane == 0) red[wave] = m;
    __syncthreads();
    m = fmaxf(fmaxf(red[0], red[1]), fmaxf(red[2], red[3]));
    float s = 0.f;
    #pragma unroll
    for (int i = 0; i < 8; i++) { f[i] = __expf(f[i] - m); s += f[i]; }
    #pragma unroll
    for (int off = 1; off < 64; off <<= 1) s += __shfl_xor(s, off);
    if (lane == 0) red2[wave] = s;
    __syncthreads();
    s = red2[0] + red2[1] + red2[2] + red2[3];
    float inv = 1.f / s;
    #pragma unroll
    for (int i = 0; i < 8; i++)
        attn[b * 2048 + i * 256 + tid] = f[i] * inv;
}

// ---- kernel 3: partial context: part[b][ch][d] = sum_{t in 64-chunk} attn*h_enc
__global__ void kctx(const float* __restrict__ A, const float* __restrict__ attn,
                     float* __restrict__ part) {
    __shared__ float at[64];
    __shared__ float4 red[128];
    int b = blockIdx.x, ch = blockIdx.y, tid = threadIdx.x;
    if (tid < 64) at[tid] = attn[b * 2048 + ch * 64 + tid];
    __syncthreads();
    int dt = tid & 127, th = tid >> 7;
    const float* base = A + ((size_t)b * 2048 + ch * 64 + th * 32) * 512 + dt * 4;
    const float* aw = at + th * 32;
    float4 acc = (float4){0.f, 0.f, 0.f, 0.f};
    #pragma unroll 8
    for (int tt = 0; tt < 32; ++tt) {
        float a = aw[tt];
        float4 h = *(const float4*)(base + (size_t)tt * 512);
        acc.x += a * h.x; acc.y += a * h.y; acc.z += a * h.z; acc.w += a * h.w;
    }
    if (th == 1) red[dt] = acc;
    __syncthreads();
    if (th == 0) {
        float4 o = red[dt];
        float4 r; r.x = acc.x + o.x; r.y = acc.y + o.y;
        r.z = acc.z + o.z; r.w = acc.w + o.w;
        *(float4*)(part + ((size_t)b * 32 + ch) * 512 + dt * 4) = r;
    }
}

// ---- kernel 4: ctx[b][d] = sum_ch part[b][ch][d]
__global__ void kfin(const float* __restrict__ part, float* __restrict__ ctx) {
    int idx = blockIdx.x * 256 + threadIdx.x;   // 0..16383
    int b = idx >> 9, d = idx & 511;
    const float* p = part + (size_t)b * 32 * 512 + d;
    float s = 0.f;
    #pragma unroll
    for (int cI = 0; cI < 32; ++cI) s += p[cI * 512];
    ctx[idx] = s;
}

extern "C" void kernel_launch(void* const* d_in, const int* in_sizes, int n_in,
                              void* d_out, int out_size, void* d_ws, size_t ws_size,
                              hipStream_t stream) {
    const float* h_enc = (const float*)d_in[0];
    const float* h_dec = (const float*)d_in[1];
    const float* W1    = (const float*)d_in[2];
    const float* b1    = (const float*)d_in[3];
    const float* W2    = (const float*)d_in[4];
    const float* b2    = (const float*)d_in[5];
    float* out  = (float*)d_out;
    float* ctx  = out;              // 32*512
    float* attn = out + 32 * 512;   // 32*2048

    char* ws = (char*)d_ws;
    ushort* Wp = (ushort*)ws;                                    // 512 KB
    float* dec  = (float*)(ws + (512 * 512 * 2));                // 64 KB
    float* e2   = (float*)(ws + (512 * 512 * 2) + (32 * 512 * 4));              // 256 KB
    float* part = (float*)(ws + (512 * 512 * 2) + (32 * 512 * 4) + (65536 * 4)); // 2 MB

    kprep<<<384, 256, 0, stream>>>(W1, h_dec, b1, Wp, dec);
    kgemm<<<1024, 256, 0, stream>>>(h_enc, Wp, dec, W2, e2);
    ksoftmax<<<32, 256, 0, stream>>>(e2, b2, attn);
    dim3 g3(32, 32);
    kctx<<<g3, 256, 0, stream>>>(h_enc, attn, part);
    kfin<<<64, 256, 0, stream>>>(part, ctx);
}